// Round 12
// baseline (1253.639 us; speedup 1.0000x reference)
//
#include <hip/hip_runtime.h>

// SurfaceTransolver round 12: exact round-10 structure (best: 1187us) +
// NON-TEMPORAL STORES ONLY (out in pass3T, partials in pass1T2).
//   Model: per XCD, 32 blocks stream ~4MB x/out per tile period = one L2
//   generation -> evicts the 832KB weight set (63% hit). nt stores stop the
//   out-stream from allocating L2 lines; loads untouched (r6: nt loads hurt).
// pass1T2 (TT=64, grid 512), pass3T (TT=64, grid 256): round-10 verbatim math.

#define HID 256
#define NH  8
#define DH  32
#define NS  64
#define NQ  512
#define TT  64
#define PSTRIDE 16896

typedef short bf16x8 __attribute__((ext_vector_type(8)));
typedef short bf16x4 __attribute__((ext_vector_type(4)));
typedef float f32x4 __attribute__((ext_vector_type(4)));

#define MFMA(a,b,c) __builtin_amdgcn_mfma_f32_16x16x32_bf16((a),(b),(c),0,0,0)

__device__ __forceinline__ f32x4 mfma16(bf16x4 a, bf16x4 b, f32x4 c) {
#if __has_builtin(__builtin_amdgcn_mfma_f32_16x16x16bf16_1k)
  return __builtin_amdgcn_mfma_f32_16x16x16bf16_1k(a, b, c, 0, 0, 0);
#elif __has_builtin(__builtin_amdgcn_mfma_f32_16x16x16_bf16)
  return __builtin_amdgcn_mfma_f32_16x16x16_bf16(a, b, c, 0, 0, 0);
#else
  f32x4 d;
  asm("v_mfma_f32_16x16x16_bf16 %0, %1, %2, %3" : "=v"(d) : "v"(a), "v"(b), "v"(c));
  return d;
#endif
}

__device__ __forceinline__ f32x4 zero4() { f32x4 z; z[0]=0.f; z[1]=0.f; z[2]=0.f; z[3]=0.f; return z; }

__device__ __forceinline__ ushort bf_rne(float f) {
  unsigned u = __float_as_uint(f);
  return (ushort)((u + 0x7FFFu + ((u >> 16) & 1u)) >> 16);
}
__device__ __forceinline__ void split2(float f, ushort& h, ushort& l) {
  h = bf_rne(f);
  float fh = __uint_as_float(((unsigned)h) << 16);
  l = bf_rne(f - fh);
}
__device__ __forceinline__ uint pack2(float f) {
  ushort h, l; split2(f, h, l);
  return ((uint)h << 16) | (uint)l;
}
__device__ __forceinline__ bf16x4 pack4(float a0, float a1, float a2, float a3) {
  union { ushort u[4]; bf16x4 v; } P;
  P.u[0] = bf_rne(a0); P.u[1] = bf_rne(a1); P.u[2] = bf_rne(a2); P.u[3] = bf_rne(a3);
  return P.v;
}

// ---------------- K0a ----------------
__global__ __launch_bounds__(256) void k_build_wlog(
    const float* __restrict__ Wx, const float* __restrict__ bx,
    const float* __restrict__ Wsl, const float* __restrict__ bsl,
    const float* __restrict__ temp,
    ushort* __restrict__ wlh, ushort* __restrict__ wll, float* __restrict__ blog)
{
  const int q = blockIdx.x, k = threadIdx.x;
  const int h = q >> 6, s = q & 63;
  const float it = 1.0f / temp[h];
  float acc = 0.f;
#pragma unroll
  for (int c = 0; c < DH; ++c)
    acc = fmaf(Wx[k * HID + h * DH + c], Wsl[c * NS + s], acc);
  acc *= it;
  ushort hh, ll; split2(acc, hh, ll);
  wlh[q * HID + k] = hh; wll[q * HID + k] = ll;
  if (k == 0) {
    float b = bsl[s];
    for (int c = 0; c < DH; ++c) b = fmaf(bx[h * DH + c], Wsl[c * NS + s], b);
    blog[q] = b * it;
  }
}

// ---------------- K0b ----------------
__global__ __launch_bounds__(256) void k_build_wfxt(
    const float* __restrict__ Wfx, ushort* __restrict__ wfxth)
{
  const int c = blockIdx.x, k = threadIdx.x;
  wfxth[c * HID + k] = bf_rne(Wfx[k * HID + c]);
}

// ---------------- K0c ----------------
__global__ __launch_bounds__(256) void k_build_wprojt(
    const float* __restrict__ Wproj, ushort* __restrict__ wpth, ushort* __restrict__ wptl)
{
  const int hc = blockIdx.x, j = threadIdx.x;
  ushort hh, ll; split2(Wproj[hc * HID + j], hh, ll);
  wpth[j * HID + hc] = hh; wptl[j * HID + hc] = ll;
}

// ---------------- Pass 1T2 (round-10 verbatim + nt partials stores) ----------------
__global__ __launch_bounds__(512, 1) void k_pass1T2(
    const float* __restrict__ x, const float* __restrict__ mask,
    const ushort* __restrict__ wlogh, const float* __restrict__ blog,
    const ushort* __restrict__ wfxth, const float* __restrict__ bfx,
    float* __restrict__ partials, int Ntok, int ntiles, int ngrid)
{
  __shared__ ushort xh[TT * 264];
  __shared__ float msk[TT];

  const int t = threadIdx.x;
  const int wv = t >> 6, lane = t & 63, lr = lane & 15, lg = lane >> 4;
  const int h = wv;

  float blogr[4], bfxr[2];
#pragma unroll
  for (int cf = 0; cf < 4; ++cf) blogr[cf] = blog[h * 64 + cf * 16 + lr];
#pragma unroll
  for (int cf2 = 0; cf2 < 2; ++cf2) bfxr[cf2] = bfx[h * 32 + cf2 * 16 + lr];

  f32x4 pool[4][2];
#pragma unroll
  for (int cf = 0; cf < 4; ++cf) { pool[cf][0] = zero4(); pool[cf][1] = zero4(); }
  float nacc[4] = {0.f, 0.f, 0.f, 0.f};

  for (int tile = blockIdx.x; tile < ntiles; tile += ngrid) {
    const int n0 = tile * TT;
    __syncthreads();
    {
      const int tok = t >> 3, seg = (t & 7) * 32;
      const int n = n0 + tok;
      const float* xrow = x + (size_t)n * HID + seg;
#pragma unroll
      for (int g = 0; g < 4; ++g) {
        float v[8];
        if (n < Ntok) {
          const float4* xp = (const float4*)(xrow + g * 8);
          float4 f0 = xp[0], f1 = xp[1];
          v[0]=f0.x; v[1]=f0.y; v[2]=f0.z; v[3]=f0.w;
          v[4]=f1.x; v[5]=f1.y; v[6]=f1.z; v[7]=f1.w;
        } else {
#pragma unroll
          for (int i = 0; i < 8; ++i) v[i] = 0.f;
        }
        union { ushort u[8]; bf16x8 v8; } H;
#pragma unroll
        for (int i = 0; i < 8; ++i) H.u[i] = bf_rne(v[i]);
        *reinterpret_cast<bf16x8*>(&xh[tok * 264 + seg + g * 8]) = H.v8;
      }
      if (t < TT) msk[t] = (n0 + t < Ntok) ? mask[n0 + t] : 0.f;
    }
    __syncthreads();

    f32x4 acc[4][4];
#pragma unroll
    for (int rf = 0; rf < 4; ++rf)
#pragma unroll
      for (int cf = 0; cf < 4; ++cf) acc[rf][cf] = zero4();
#pragma unroll
    for (int kk = 0; kk < 8; ++kk) {
      bf16x8 a[4];
#pragma unroll
      for (int rf = 0; rf < 4; ++rf)
        a[rf] = *reinterpret_cast<const bf16x8*>(&xh[(rf * 16 + lr) * 264 + kk * 32 + lg * 8]);
#pragma unroll
      for (int cf = 0; cf < 4; ++cf) {
        bf16x8 bh = *reinterpret_cast<const bf16x8*>(wlogh + (size_t)(h * 64 + cf * 16 + lr) * HID + kk * 32 + lg * 8);
#pragma unroll
        for (int rf = 0; rf < 4; ++rf) acc[rf][cf] = MFMA(a[rf], bh, acc[rf][cf]);
      }
    }
    bf16x4 aw[4][4];
#pragma unroll
    for (int rf = 0; rf < 4; ++rf) {
#pragma unroll
      for (int r = 0; r < 4; ++r) {
        float mx = -1e30f;
#pragma unroll
        for (int cf = 0; cf < 4; ++cf) { float vv = acc[rf][cf][r] + blogr[cf]; acc[rf][cf][r] = vv; mx = fmaxf(mx, vv); }
        mx = fmaxf(mx, __shfl_xor(mx, 1)); mx = fmaxf(mx, __shfl_xor(mx, 2));
        mx = fmaxf(mx, __shfl_xor(mx, 4)); mx = fmaxf(mx, __shfl_xor(mx, 8));
        float sm = 0.f;
#pragma unroll
        for (int cf = 0; cf < 4; ++cf) { float e = __expf(acc[rf][cf][r] - mx); acc[rf][cf][r] = e; sm += e; }
        sm += __shfl_xor(sm, 1); sm += __shfl_xor(sm, 2); sm += __shfl_xor(sm, 4); sm += __shfl_xor(sm, 8);
        const float sc = msk[rf * 16 + lg * 4 + r] / sm;
#pragma unroll
        for (int cf = 0; cf < 4; ++cf) { acc[rf][cf][r] *= sc; nacc[cf] += acc[rf][cf][r]; }
      }
#pragma unroll
      for (int cf = 0; cf < 4; ++cf)
        aw[rf][cf] = pack4(acc[rf][cf][0], acc[rf][cf][1], acc[rf][cf][2], acc[rf][cf][3]);
    }
    f32x4 fa[4][2];
#pragma unroll
    for (int rf = 0; rf < 4; ++rf) { fa[rf][0] = zero4(); fa[rf][1] = zero4(); }
#pragma unroll
    for (int kk = 0; kk < 8; ++kk) {
      bf16x8 a[4];
#pragma unroll
      for (int rf = 0; rf < 4; ++rf)
        a[rf] = *reinterpret_cast<const bf16x8*>(&xh[(rf * 16 + lr) * 264 + kk * 32 + lg * 8]);
#pragma unroll
      for (int cf2 = 0; cf2 < 2; ++cf2) {
        bf16x8 bf = *reinterpret_cast<const bf16x8*>(wfxth + (size_t)(h * 32 + cf2 * 16 + lr) * HID + kk * 32 + lg * 8);
#pragma unroll
        for (int rf = 0; rf < 4; ++rf) fa[rf][cf2] = MFMA(a[rf], bf, fa[rf][cf2]);
      }
    }
#pragma unroll
    for (int rf = 0; rf < 4; ++rf) {
      bf16x4 bfrag[2];
#pragma unroll
      for (int cf2 = 0; cf2 < 2; ++cf2)
        bfrag[cf2] = pack4(fa[rf][cf2][0] + bfxr[cf2], fa[rf][cf2][1] + bfxr[cf2],
                           fa[rf][cf2][2] + bfxr[cf2], fa[rf][cf2][3] + bfxr[cf2]);
#pragma unroll
      for (int cf = 0; cf < 4; ++cf)
#pragma unroll
        for (int cf2 = 0; cf2 < 2; ++cf2)
          pool[cf][cf2] = mfma16(aw[rf][cf], bfrag[cf2], pool[cf][cf2]);
    }
  }
  float* pb = partials + (size_t)blockIdx.x * PSTRIDE;
#pragma unroll
  for (int cf = 0; cf < 4; ++cf)
#pragma unroll
    for (int cf2 = 0; cf2 < 2; ++cf2)
#pragma unroll
      for (int r = 0; r < 4; ++r) {
        const int s = cf * 16 + lg * 4 + r;
        const int hcl = cf2 * 16 + lr;
        __builtin_nontemporal_store(pool[cf][cf2][r], &pb[h * 2048 + s * 32 + hcl]);
      }
#pragma unroll
  for (int cf = 0; cf < 4; ++cf) {
    float v = nacc[cf];
    v += __shfl_xor(v, 16); v += __shfl_xor(v, 32);
    if (lg == 0) __builtin_nontemporal_store(v, &pb[16384 + h * 64 + cf * 16 + lr]);
  }
}

// ---------------- reductions ----------------
__global__ __launch_bounds__(256) void k_reduce_norm(
    const float* __restrict__ partials, float* __restrict__ normbuf, int nb)
{
  const int p = blockIdx.x * 256 + threadIdx.x;
  float s = 0.f;
  for (int b = 0; b < nb; ++b) s += partials[(size_t)b * PSTRIDE + 16384 + p];
  normbuf[p] = s;
}

__global__ __launch_bounds__(256) void k_reduce_num(
    const float* __restrict__ partials, const float* __restrict__ normbuf,
    float* __restrict__ st, int nb)
{
  const int pidx = blockIdx.x * 256 + threadIdx.x;
  float acc = 0.f;
  for (int b = 0; b < nb; ++b) acc += partials[(size_t)b * PSTRIDE + pidx];
  st[pidx] = acc / (normbuf[pidx >> 5] + 1e-5f);
}

// ---------------- SDPA ----------------
__global__ __launch_bounds__(64) void k_sdpa(
    const float* __restrict__ st, const float* __restrict__ Wqkv,
    uint* __restrict__ osltp)
{
  __shared__ float stt[NS][DH + 1];
  __shared__ float kt[NS][DH + 1];
  __shared__ float vt[NS][DH + 1];
  const int h = blockIdx.x, sr = threadIdx.x;
  for (int i = sr; i < NS * DH; i += 64) stt[i >> 5][i & 31] = st[(size_t)h * NS * DH + i];
  __syncthreads();
  float qr[DH];
#pragma unroll
  for (int c = 0; c < DH; ++c) {
    float aq = 0.f, ak = 0.f, av = 0.f;
#pragma unroll
    for (int i = 0; i < DH; ++i) {
      const float sv = stt[sr][i];
      aq = fmaf(sv, Wqkv[i * 96 + c], aq);
      ak = fmaf(sv, Wqkv[i * 96 + 32 + c], ak);
      av = fmaf(sv, Wqkv[i * 96 + 64 + c], av);
    }
    qr[c] = aq; kt[sr][c] = ak; vt[sr][c] = av;
  }
  __syncthreads();
  float sc[NS];
  float m = -1e30f;
  const float scale = 0.17677669529663687f;
#pragma unroll
  for (int tt = 0; tt < NS; ++tt) {
    float a = 0.f;
#pragma unroll
    for (int c = 0; c < DH; ++c) a = fmaf(qr[c], kt[tt][c], a);
    a *= scale; sc[tt] = a; m = fmaxf(m, a);
  }
  float sum = 0.f;
#pragma unroll
  for (int tt = 0; tt < NS; ++tt) { const float e = __expf(sc[tt] - m); sc[tt] = e; sum += e; }
  const float inv = 1.f / sum;
#pragma unroll
  for (int c = 0; c < DH; ++c) {
    float o = 0.f;
#pragma unroll
    for (int tt = 0; tt < NS; ++tt) o = fmaf(sc[tt], vt[tt][c], o);
    o *= inv;
    osltp[(h * DH + c) * NS + sr] = pack2(o);
  }
}

// ---------------- Pass 3T (round-10 verbatim + nt out stores) ----------------
__global__ __launch_bounds__(512, 2) void k_pass3T(
    const float* __restrict__ x, const float* __restrict__ mask,
    const ushort* __restrict__ wlogh, const ushort* __restrict__ wlogl,
    const float* __restrict__ blog,
    const uint* __restrict__ osltp,
    const ushort* __restrict__ wpth, const ushort* __restrict__ wptl,
    const float* __restrict__ bproj,
    float* __restrict__ out, int Ntok, int ntiles, int ngrid)
{
  __shared__ uint smem[TT * 268];
  __shared__ float msk[TT];
  ushort* xh = (ushort*)smem;
  ushort* xl = xh + TT * 264;
  uint*   ox32 = smem;
  float*  outs = (float*)smem;

  const int t = threadIdx.x;
  const int wv = t >> 6, lane = t & 63, lr = lane & 15, lg = lane >> 4;
  const int h = wv;

  float bprr[2];
#pragma unroll
  for (int cf = 0; cf < 2; ++cf) bprr[cf] = bproj[wv * 32 + cf * 16 + lr];
  float4 blgv[4];
#pragma unroll
  for (int cf = 0; cf < 4; ++cf)
    blgv[cf] = *reinterpret_cast<const float4*>(blog + h * 64 + cf * 16 + lg * 4);

  bf16x4 oslh[2][4], osll[2][4];
#pragma unroll
  for (int cfo = 0; cfo < 2; ++cfo)
#pragma unroll
    for (int sb = 0; sb < 4; ++sb) {
      const uint4 q = *reinterpret_cast<const uint4*>(
          osltp + (size_t)(h * DH + cfo * 16 + lr) * NS + sb * 16 + lg * 4);
      union { uint u[2]; bf16x4 v; } Hc, Lc;
      Hc.u[0] = __builtin_amdgcn_perm(q.y, q.x, 0x07060302u);
      Hc.u[1] = __builtin_amdgcn_perm(q.w, q.z, 0x07060302u);
      Lc.u[0] = __builtin_amdgcn_perm(q.y, q.x, 0x05040100u);
      Lc.u[1] = __builtin_amdgcn_perm(q.w, q.z, 0x05040100u);
      oslh[cfo][sb] = Hc.v; osll[cfo][sb] = Lc.v;
    }

  for (int tile = blockIdx.x; tile < ntiles; tile += ngrid) {
    const int n0 = tile * TT;
    __syncthreads();
    {
      const int tok = t >> 3, seg = (t & 7) * 32;
      const int n = n0 + tok;
      const float* xrow = x + (size_t)n * HID + seg;
#pragma unroll
      for (int g = 0; g < 4; ++g) {
        float v[8];
        if (n < Ntok) {
          const float4* xp = (const float4*)(xrow + g * 8);
          float4 f0 = xp[0], f1 = xp[1];
          v[0]=f0.x; v[1]=f0.y; v[2]=f0.z; v[3]=f0.w;
          v[4]=f1.x; v[5]=f1.y; v[6]=f1.z; v[7]=f1.w;
        } else {
#pragma unroll
          for (int i = 0; i < 8; ++i) v[i] = 0.f;
        }
        union { ushort u[8]; bf16x8 v8; } H, L;
#pragma unroll
        for (int i = 0; i < 8; ++i) split2(v[i], H.u[i], L.u[i]);
        *reinterpret_cast<bf16x8*>(&xh[tok * 264 + seg + g * 8]) = H.v8;
        *reinterpret_cast<bf16x8*>(&xl[tok * 264 + seg + g * 8]) = L.v8;
      }
      if (t < TT) msk[t] = (n0 + t < Ntok) ? mask[n0 + t] : 0.f;
    }
    __syncthreads();

    f32x4 acc[4][4];
#pragma unroll
    for (int rf = 0; rf < 4; ++rf)
#pragma unroll
      for (int cf = 0; cf < 4; ++cf) acc[rf][cf] = zero4();
#pragma unroll
    for (int kk = 0; kk < 8; ++kk) {
      bf16x8 bx_h[4], bx_l[4];
#pragma unroll
      for (int rf = 0; rf < 4; ++rf) {
        bx_h[rf] = *reinterpret_cast<const bf16x8*>(&xh[(rf * 16 + lr) * 264 + kk * 32 + lg * 8]);
        bx_l[rf] = *reinterpret_cast<const bf16x8*>(&xl[(rf * 16 + lr) * 264 + kk * 32 + lg * 8]);
      }
#pragma unroll
      for (int cf = 0; cf < 4; ++cf) {
        const size_t bo = (size_t)(h * 64 + cf * 16 + lr) * HID + kk * 32 + lg * 8;
        bf16x8 ah = *reinterpret_cast<const bf16x8*>(wlogh + bo);
        bf16x8 al = *reinterpret_cast<const bf16x8*>(wlogl + bo);
#pragma unroll
        for (int rf = 0; rf < 4; ++rf) {
          acc[rf][cf] = MFMA(ah, bx_h[rf], acc[rf][cf]);
          acc[rf][cf] = MFMA(al, bx_h[rf], acc[rf][cf]);
          acc[rf][cf] = MFMA(ah, bx_l[rf], acc[rf][cf]);
        }
      }
    }
#pragma unroll
    for (int rf = 0; rf < 4; ++rf) {
      float mx = -1e30f;
#pragma unroll
      for (int cf = 0; cf < 4; ++cf)
#pragma unroll
        for (int r = 0; r < 4; ++r) {
          float vv = acc[rf][cf][r] + ((const float*)&blgv[cf])[r];
          acc[rf][cf][r] = vv; mx = fmaxf(mx, vv);
        }
      mx = fmaxf(mx, __shfl_xor(mx, 16)); mx = fmaxf(mx, __shfl_xor(mx, 32));
      float sm = 0.f;
#pragma unroll
      for (int cf = 0; cf < 4; ++cf)
#pragma unroll
        for (int r = 0; r < 4; ++r) { float e = __expf(acc[rf][cf][r] - mx); acc[rf][cf][r] = e; sm += e; }
      sm += __shfl_xor(sm, 16); sm += __shfl_xor(sm, 32);
      const float sc = msk[rf * 16 + lr] / sm;
#pragma unroll
      for (int cf = 0; cf < 4; ++cf)
#pragma unroll
        for (int r = 0; r < 4; ++r) acc[rf][cf][r] *= sc;
    }
    f32x4 oxacc[4][2];
#pragma unroll
    for (int rf = 0; rf < 4; ++rf) { oxacc[rf][0] = zero4(); oxacc[rf][1] = zero4(); }
#pragma unroll
    for (int rf = 0; rf < 4; ++rf) {
      uint w32[4][4];
#pragma unroll
      for (int cf = 0; cf < 4; ++cf)
#pragma unroll
        for (int r = 0; r < 4; ++r) w32[cf][r] = pack2(acc[rf][cf][r]);
#pragma unroll
      for (int sb = 0; sb < 4; ++sb) {
        union { uint u[2]; bf16x4 v; } Hc, Lc;
        Hc.u[0] = __builtin_amdgcn_perm(w32[sb][1], w32[sb][0], 0x07060302u);
        Hc.u[1] = __builtin_amdgcn_perm(w32[sb][3], w32[sb][2], 0x07060302u);
        Lc.u[0] = __builtin_amdgcn_perm(w32[sb][1], w32[sb][0], 0x05040100u);
        Lc.u[1] = __builtin_amdgcn_perm(w32[sb][3], w32[sb][2], 0x05040100u);
#pragma unroll
        for (int cfo = 0; cfo < 2; ++cfo) {
          oxacc[rf][cfo] = mfma16(Hc.v, oslh[cfo][sb], oxacc[rf][cfo]);
          oxacc[rf][cfo] = mfma16(Lc.v, oslh[cfo][sb], oxacc[rf][cfo]);
          oxacc[rf][cfo] = mfma16(Hc.v, osll[cfo][sb], oxacc[rf][cfo]);
        }
      }
    }
    __syncthreads();
#pragma unroll
    for (int rf = 0; rf < 4; ++rf)
#pragma unroll
      for (int cfo = 0; cfo < 2; ++cfo)
#pragma unroll
        for (int r = 0; r < 4; ++r) {
          const int tok = rf * 16 + lg * 4 + r;
          const int hc = h * DH + cfo * 16 + lr;
          ox32[tok * 268 + hc] = pack2(oxacc[rf][cfo][r]);
        }
    __syncthreads();
    f32x4 s2[4][2];
#pragma unroll
    for (int rf = 0; rf < 4; ++rf) { s2[rf][0] = zero4(); s2[rf][1] = zero4(); }
#pragma unroll
    for (int kk = 0; kk < 8; ++kk) {
#pragma unroll
      for (int rf = 0; rf < 4; ++rf) {
        const uint* oxp = &ox32[(rf * 16 + lr) * 268 + kk * 32 + lg * 8];
        uint4 q0 = *reinterpret_cast<const uint4*>(oxp);
        uint4 q1 = *reinterpret_cast<const uint4*>(oxp + 4);
        union { uint u[4]; bf16x8 v; } AH, AL;
        AH.u[0] = __builtin_amdgcn_perm(q0.y, q0.x, 0x07060302u);
        AH.u[1] = __builtin_amdgcn_perm(q0.w, q0.z, 0x07060302u);
        AH.u[2] = __builtin_amdgcn_perm(q1.y, q1.x, 0x07060302u);
        AH.u[3] = __builtin_amdgcn_perm(q1.w, q1.z, 0x07060302u);
        AL.u[0] = __builtin_amdgcn_perm(q0.y, q0.x, 0x05040100u);
        AL.u[1] = __builtin_amdgcn_perm(q0.w, q0.z, 0x05040100u);
        AL.u[2] = __builtin_amdgcn_perm(q1.y, q1.x, 0x05040100u);
        AL.u[3] = __builtin_amdgcn_perm(q1.w, q1.z, 0x05040100u);
#pragma unroll
        for (int cf = 0; cf < 2; ++cf) {
          const size_t bo = (size_t)(wv * 32 + cf * 16 + lr) * HID + kk * 32 + lg * 8;
          bf16x8 bh = *reinterpret_cast<const bf16x8*>(wpth + bo);
          bf16x8 bl = *reinterpret_cast<const bf16x8*>(wptl + bo);
          s2[rf][cf] = MFMA(AH.v, bh, s2[rf][cf]);
          s2[rf][cf] = MFMA(AL.v, bh, s2[rf][cf]);
          s2[rf][cf] = MFMA(AH.v, bl, s2[rf][cf]);
        }
      }
    }
    __syncthreads();
#pragma unroll
    for (int rf = 0; rf < 4; ++rf)
#pragma unroll
      for (int cf = 0; cf < 2; ++cf)
#pragma unroll
        for (int r = 0; r < 4; ++r) {
          const int tok = rf * 16 + lg * 4 + r;
          const int j = wv * 32 + cf * 16 + lr;
          const float mk = msk[tok];
          outs[tok * 268 + j] = mk * (mk * s2[rf][cf][r] + bprr[cf]);
        }
    __syncthreads();
    {
      const int tok0 = t >> 8, col = t & 255;
#pragma unroll 4
      for (int rr = 0; rr < TT / 2; ++rr) {
        const int tok = rr * 2 + tok0;
        const int n = n0 + tok;
        if (n < Ntok)
          __builtin_nontemporal_store(outs[tok * 268 + col],
                                      &out[(size_t)n * HID + col]);
      }
    }
  }
}

extern "C" void kernel_launch(void* const* d_in, const int* in_sizes, int n_in,
                              void* d_out, int out_size, void* d_ws, size_t ws_size,
                              hipStream_t stream)
{
  const float* x     = (const float*)d_in[0];
  const float* mask  = (const float*)d_in[1];
  const float* Wfx   = (const float*)d_in[2];
  const float* bfx   = (const float*)d_in[3];
  const float* Wx    = (const float*)d_in[4];
  const float* bx    = (const float*)d_in[5];
  const float* Wsl   = (const float*)d_in[6];
  const float* bsl   = (const float*)d_in[7];
  const float* Wqkv  = (const float*)d_in[8];
  const float* Wproj = (const float*)d_in[9];
  const float* bproj = (const float*)d_in[10];
  const float* temp  = (const float*)d_in[11];
  float* out = (float*)d_out;

  const int Ntok = in_sizes[0] / HID;
  const int ntiles = (Ntok + TT - 1) / TT;     // 3125 exact

  char* ws = (char*)d_ws;
  size_t off = 0;
  ushort* wlogh = (ushort*)(ws + off); off += (size_t)NQ * HID * 2;
  ushort* wlogl = (ushort*)(ws + off); off += (size_t)NQ * HID * 2;
  float*  blog  = (float*)(ws + off);  off += NQ * 4;
  ushort* wfxth = (ushort*)(ws + off); off += (size_t)HID * HID * 2;
  ushort* wpth  = (ushort*)(ws + off); off += (size_t)HID * HID * 2;
  ushort* wptl  = (ushort*)(ws + off); off += (size_t)HID * HID * 2;
  uint*   osltp = (uint*)(ws + off);   off += (size_t)NQ * DH * 4;
  float*  stb   = (float*)(ws + off);  off += (size_t)NQ * DH * 4;
  float*  normb = (float*)(ws + off);  off += NQ * 4;
  int nbp = 512;
  while (nbp > 1 && off + (size_t)nbp * PSTRIDE * 4 > ws_size) nbp >>= 1;
  float* partials = (float*)(ws + off);

  k_build_wlog<<<dim3(NQ), dim3(256), 0, stream>>>(Wx, bx, Wsl, bsl, temp, wlogh, wlogl, blog);
  k_build_wfxt<<<dim3(HID), dim3(256), 0, stream>>>(Wfx, wfxth);
  k_build_wprojt<<<dim3(HID), dim3(256), 0, stream>>>(Wproj, wpth, wptl);
  k_pass1T2<<<dim3(nbp), dim3(512), 0, stream>>>(x, mask, wlogh, blog, wfxth, bfx,
                                                 partials, Ntok, ntiles, nbp);
  k_reduce_norm<<<dim3(2), dim3(256), 0, stream>>>(partials, normb, nbp);
  k_reduce_num<<<dim3(64), dim3(256), 0, stream>>>(partials, normb, stb, nbp);
  k_sdpa<<<dim3(NH), dim3(64), 0, stream>>>(stb, Wqkv, osltp);
  k_pass3T<<<dim3(256), dim3(512), 0, stream>>>(x, mask, wlogh, wlogl, blog,
                                                osltp, wpth, wptl, bproj,
                                                out, Ntok, ntiles, 256);
}

// Round 13
// 1106.303 us; speedup vs baseline: 1.1332x; 1.1332x over previous
//
#include <hip/hip_runtime.h>

// SurfaceTransolver round 13: convergence — best-of recombination.
//   pass1T2: round-10 verbatim (PLAIN partials stores; r12's nt partials
//            regressed ~70us: partials are producer->consumer, nt evicts them
//            to HBM before k_reduce_* re-reads).
//   pass3T : round-12 verbatim (nt OUT stores only; confirmed -25us: out is
//            never re-read, nt stops its L2 allocation from evicting weights).
// Everything else identical to round 10 (best total: 1187us).

#define HID 256
#define NH  8
#define DH  32
#define NS  64
#define NQ  512
#define TT  64
#define PSTRIDE 16896

typedef short bf16x8 __attribute__((ext_vector_type(8)));
typedef short bf16x4 __attribute__((ext_vector_type(4)));
typedef float f32x4 __attribute__((ext_vector_type(4)));

#define MFMA(a,b,c) __builtin_amdgcn_mfma_f32_16x16x32_bf16((a),(b),(c),0,0,0)

__device__ __forceinline__ f32x4 mfma16(bf16x4 a, bf16x4 b, f32x4 c) {
#if __has_builtin(__builtin_amdgcn_mfma_f32_16x16x16bf16_1k)
  return __builtin_amdgcn_mfma_f32_16x16x16bf16_1k(a, b, c, 0, 0, 0);
#elif __has_builtin(__builtin_amdgcn_mfma_f32_16x16x16_bf16)
  return __builtin_amdgcn_mfma_f32_16x16x16_bf16(a, b, c, 0, 0, 0);
#else
  f32x4 d;
  asm("v_mfma_f32_16x16x16_bf16 %0, %1, %2, %3" : "=v"(d) : "v"(a), "v"(b), "v"(c));
  return d;
#endif
}

__device__ __forceinline__ f32x4 zero4() { f32x4 z; z[0]=0.f; z[1]=0.f; z[2]=0.f; z[3]=0.f; return z; }

__device__ __forceinline__ ushort bf_rne(float f) {
  unsigned u = __float_as_uint(f);
  return (ushort)((u + 0x7FFFu + ((u >> 16) & 1u)) >> 16);
}
__device__ __forceinline__ void split2(float f, ushort& h, ushort& l) {
  h = bf_rne(f);
  float fh = __uint_as_float(((unsigned)h) << 16);
  l = bf_rne(f - fh);
}
__device__ __forceinline__ uint pack2(float f) {
  ushort h, l; split2(f, h, l);
  return ((uint)h << 16) | (uint)l;
}
__device__ __forceinline__ bf16x4 pack4(float a0, float a1, float a2, float a3) {
  union { ushort u[4]; bf16x4 v; } P;
  P.u[0] = bf_rne(a0); P.u[1] = bf_rne(a1); P.u[2] = bf_rne(a2); P.u[3] = bf_rne(a3);
  return P.v;
}

// ---------------- K0a ----------------
__global__ __launch_bounds__(256) void k_build_wlog(
    const float* __restrict__ Wx, const float* __restrict__ bx,
    const float* __restrict__ Wsl, const float* __restrict__ bsl,
    const float* __restrict__ temp,
    ushort* __restrict__ wlh, ushort* __restrict__ wll, float* __restrict__ blog)
{
  const int q = blockIdx.x, k = threadIdx.x;
  const int h = q >> 6, s = q & 63;
  const float it = 1.0f / temp[h];
  float acc = 0.f;
#pragma unroll
  for (int c = 0; c < DH; ++c)
    acc = fmaf(Wx[k * HID + h * DH + c], Wsl[c * NS + s], acc);
  acc *= it;
  ushort hh, ll; split2(acc, hh, ll);
  wlh[q * HID + k] = hh; wll[q * HID + k] = ll;
  if (k == 0) {
    float b = bsl[s];
    for (int c = 0; c < DH; ++c) b = fmaf(bx[h * DH + c], Wsl[c * NS + s], b);
    blog[q] = b * it;
  }
}

// ---------------- K0b ----------------
__global__ __launch_bounds__(256) void k_build_wfxt(
    const float* __restrict__ Wfx, ushort* __restrict__ wfxth)
{
  const int c = blockIdx.x, k = threadIdx.x;
  wfxth[c * HID + k] = bf_rne(Wfx[k * HID + c]);
}

// ---------------- K0c ----------------
__global__ __launch_bounds__(256) void k_build_wprojt(
    const float* __restrict__ Wproj, ushort* __restrict__ wpth, ushort* __restrict__ wptl)
{
  const int hc = blockIdx.x, j = threadIdx.x;
  ushort hh, ll; split2(Wproj[hc * HID + j], hh, ll);
  wpth[j * HID + hc] = hh; wptl[j * HID + hc] = ll;
}

// ---------------- Pass 1T2 (round-10 verbatim, plain stores) ----------------
__global__ __launch_bounds__(512, 1) void k_pass1T2(
    const float* __restrict__ x, const float* __restrict__ mask,
    const ushort* __restrict__ wlogh, const float* __restrict__ blog,
    const ushort* __restrict__ wfxth, const float* __restrict__ bfx,
    float* __restrict__ partials, int Ntok, int ntiles, int ngrid)
{
  __shared__ ushort xh[TT * 264];
  __shared__ float msk[TT];

  const int t = threadIdx.x;
  const int wv = t >> 6, lane = t & 63, lr = lane & 15, lg = lane >> 4;
  const int h = wv;

  float blogr[4], bfxr[2];
#pragma unroll
  for (int cf = 0; cf < 4; ++cf) blogr[cf] = blog[h * 64 + cf * 16 + lr];
#pragma unroll
  for (int cf2 = 0; cf2 < 2; ++cf2) bfxr[cf2] = bfx[h * 32 + cf2 * 16 + lr];

  f32x4 pool[4][2];
#pragma unroll
  for (int cf = 0; cf < 4; ++cf) { pool[cf][0] = zero4(); pool[cf][1] = zero4(); }
  float nacc[4] = {0.f, 0.f, 0.f, 0.f};

  for (int tile = blockIdx.x; tile < ntiles; tile += ngrid) {
    const int n0 = tile * TT;
    __syncthreads();
    {
      const int tok = t >> 3, seg = (t & 7) * 32;
      const int n = n0 + tok;
      const float* xrow = x + (size_t)n * HID + seg;
#pragma unroll
      for (int g = 0; g < 4; ++g) {
        float v[8];
        if (n < Ntok) {
          const float4* xp = (const float4*)(xrow + g * 8);
          float4 f0 = xp[0], f1 = xp[1];
          v[0]=f0.x; v[1]=f0.y; v[2]=f0.z; v[3]=f0.w;
          v[4]=f1.x; v[5]=f1.y; v[6]=f1.z; v[7]=f1.w;
        } else {
#pragma unroll
          for (int i = 0; i < 8; ++i) v[i] = 0.f;
        }
        union { ushort u[8]; bf16x8 v8; } H;
#pragma unroll
        for (int i = 0; i < 8; ++i) H.u[i] = bf_rne(v[i]);
        *reinterpret_cast<bf16x8*>(&xh[tok * 264 + seg + g * 8]) = H.v8;
      }
      if (t < TT) msk[t] = (n0 + t < Ntok) ? mask[n0 + t] : 0.f;
    }
    __syncthreads();

    f32x4 acc[4][4];
#pragma unroll
    for (int rf = 0; rf < 4; ++rf)
#pragma unroll
      for (int cf = 0; cf < 4; ++cf) acc[rf][cf] = zero4();
#pragma unroll
    for (int kk = 0; kk < 8; ++kk) {
      bf16x8 a[4];
#pragma unroll
      for (int rf = 0; rf < 4; ++rf)
        a[rf] = *reinterpret_cast<const bf16x8*>(&xh[(rf * 16 + lr) * 264 + kk * 32 + lg * 8]);
#pragma unroll
      for (int cf = 0; cf < 4; ++cf) {
        bf16x8 bh = *reinterpret_cast<const bf16x8*>(wlogh + (size_t)(h * 64 + cf * 16 + lr) * HID + kk * 32 + lg * 8);
#pragma unroll
        for (int rf = 0; rf < 4; ++rf) acc[rf][cf] = MFMA(a[rf], bh, acc[rf][cf]);
      }
    }
    bf16x4 aw[4][4];
#pragma unroll
    for (int rf = 0; rf < 4; ++rf) {
#pragma unroll
      for (int r = 0; r < 4; ++r) {
        float mx = -1e30f;
#pragma unroll
        for (int cf = 0; cf < 4; ++cf) { float vv = acc[rf][cf][r] + blogr[cf]; acc[rf][cf][r] = vv; mx = fmaxf(mx, vv); }
        mx = fmaxf(mx, __shfl_xor(mx, 1)); mx = fmaxf(mx, __shfl_xor(mx, 2));
        mx = fmaxf(mx, __shfl_xor(mx, 4)); mx = fmaxf(mx, __shfl_xor(mx, 8));
        float sm = 0.f;
#pragma unroll
        for (int cf = 0; cf < 4; ++cf) { float e = __expf(acc[rf][cf][r] - mx); acc[rf][cf][r] = e; sm += e; }
        sm += __shfl_xor(sm, 1); sm += __shfl_xor(sm, 2); sm += __shfl_xor(sm, 4); sm += __shfl_xor(sm, 8);
        const float sc = msk[rf * 16 + lg * 4 + r] / sm;
#pragma unroll
        for (int cf = 0; cf < 4; ++cf) { acc[rf][cf][r] *= sc; nacc[cf] += acc[rf][cf][r]; }
      }
#pragma unroll
      for (int cf = 0; cf < 4; ++cf)
        aw[rf][cf] = pack4(acc[rf][cf][0], acc[rf][cf][1], acc[rf][cf][2], acc[rf][cf][3]);
    }
    f32x4 fa[4][2];
#pragma unroll
    for (int rf = 0; rf < 4; ++rf) { fa[rf][0] = zero4(); fa[rf][1] = zero4(); }
#pragma unroll
    for (int kk = 0; kk < 8; ++kk) {
      bf16x8 a[4];
#pragma unroll
      for (int rf = 0; rf < 4; ++rf)
        a[rf] = *reinterpret_cast<const bf16x8*>(&xh[(rf * 16 + lr) * 264 + kk * 32 + lg * 8]);
#pragma unroll
      for (int cf2 = 0; cf2 < 2; ++cf2) {
        bf16x8 bf = *reinterpret_cast<const bf16x8*>(wfxth + (size_t)(h * 32 + cf2 * 16 + lr) * HID + kk * 32 + lg * 8);
#pragma unroll
        for (int rf = 0; rf < 4; ++rf) fa[rf][cf2] = MFMA(a[rf], bf, fa[rf][cf2]);
      }
    }
#pragma unroll
    for (int rf = 0; rf < 4; ++rf) {
      bf16x4 bfrag[2];
#pragma unroll
      for (int cf2 = 0; cf2 < 2; ++cf2)
        bfrag[cf2] = pack4(fa[rf][cf2][0] + bfxr[cf2], fa[rf][cf2][1] + bfxr[cf2],
                           fa[rf][cf2][2] + bfxr[cf2], fa[rf][cf2][3] + bfxr[cf2]);
#pragma unroll
      for (int cf = 0; cf < 4; ++cf)
#pragma unroll
        for (int cf2 = 0; cf2 < 2; ++cf2)
          pool[cf][cf2] = mfma16(aw[rf][cf], bfrag[cf2], pool[cf][cf2]);
    }
  }
  float* pb = partials + (size_t)blockIdx.x * PSTRIDE;
#pragma unroll
  for (int cf = 0; cf < 4; ++cf)
#pragma unroll
    for (int cf2 = 0; cf2 < 2; ++cf2)
#pragma unroll
      for (int r = 0; r < 4; ++r) {
        const int s = cf * 16 + lg * 4 + r;
        const int hcl = cf2 * 16 + lr;
        pb[h * 2048 + s * 32 + hcl] = pool[cf][cf2][r];
      }
#pragma unroll
  for (int cf = 0; cf < 4; ++cf) {
    float v = nacc[cf];
    v += __shfl_xor(v, 16); v += __shfl_xor(v, 32);
    if (lg == 0) pb[16384 + h * 64 + cf * 16 + lr] = v;
  }
}

// ---------------- reductions ----------------
__global__ __launch_bounds__(256) void k_reduce_norm(
    const float* __restrict__ partials, float* __restrict__ normbuf, int nb)
{
  const int p = blockIdx.x * 256 + threadIdx.x;
  float s = 0.f;
  for (int b = 0; b < nb; ++b) s += partials[(size_t)b * PSTRIDE + 16384 + p];
  normbuf[p] = s;
}

__global__ __launch_bounds__(256) void k_reduce_num(
    const float* __restrict__ partials, const float* __restrict__ normbuf,
    float* __restrict__ st, int nb)
{
  const int pidx = blockIdx.x * 256 + threadIdx.x;
  float acc = 0.f;
  for (int b = 0; b < nb; ++b) acc += partials[(size_t)b * PSTRIDE + pidx];
  st[pidx] = acc / (normbuf[pidx >> 5] + 1e-5f);
}

// ---------------- SDPA ----------------
__global__ __launch_bounds__(64) void k_sdpa(
    const float* __restrict__ st, const float* __restrict__ Wqkv,
    uint* __restrict__ osltp)
{
  __shared__ float stt[NS][DH + 1];
  __shared__ float kt[NS][DH + 1];
  __shared__ float vt[NS][DH + 1];
  const int h = blockIdx.x, sr = threadIdx.x;
  for (int i = sr; i < NS * DH; i += 64) stt[i >> 5][i & 31] = st[(size_t)h * NS * DH + i];
  __syncthreads();
  float qr[DH];
#pragma unroll
  for (int c = 0; c < DH; ++c) {
    float aq = 0.f, ak = 0.f, av = 0.f;
#pragma unroll
    for (int i = 0; i < DH; ++i) {
      const float sv = stt[sr][i];
      aq = fmaf(sv, Wqkv[i * 96 + c], aq);
      ak = fmaf(sv, Wqkv[i * 96 + 32 + c], ak);
      av = fmaf(sv, Wqkv[i * 96 + 64 + c], av);
    }
    qr[c] = aq; kt[sr][c] = ak; vt[sr][c] = av;
  }
  __syncthreads();
  float sc[NS];
  float m = -1e30f;
  const float scale = 0.17677669529663687f;
#pragma unroll
  for (int tt = 0; tt < NS; ++tt) {
    float a = 0.f;
#pragma unroll
    for (int c = 0; c < DH; ++c) a = fmaf(qr[c], kt[tt][c], a);
    a *= scale; sc[tt] = a; m = fmaxf(m, a);
  }
  float sum = 0.f;
#pragma unroll
  for (int tt = 0; tt < NS; ++tt) { const float e = __expf(sc[tt] - m); sc[tt] = e; sum += e; }
  const float inv = 1.f / sum;
#pragma unroll
  for (int c = 0; c < DH; ++c) {
    float o = 0.f;
#pragma unroll
    for (int tt = 0; tt < NS; ++tt) o = fmaf(sc[tt], vt[tt][c], o);
    o *= inv;
    osltp[(h * DH + c) * NS + sr] = pack2(o);
  }
}

// ---------------- Pass 3T (round-12 verbatim: nt out stores) ----------------
__global__ __launch_bounds__(512, 2) void k_pass3T(
    const float* __restrict__ x, const float* __restrict__ mask,
    const ushort* __restrict__ wlogh, const ushort* __restrict__ wlogl,
    const float* __restrict__ blog,
    const uint* __restrict__ osltp,
    const ushort* __restrict__ wpth, const ushort* __restrict__ wptl,
    const float* __restrict__ bproj,
    float* __restrict__ out, int Ntok, int ntiles, int ngrid)
{
  __shared__ uint smem[TT * 268];
  __shared__ float msk[TT];
  ushort* xh = (ushort*)smem;
  ushort* xl = xh + TT * 264;
  uint*   ox32 = smem;
  float*  outs = (float*)smem;

  const int t = threadIdx.x;
  const int wv = t >> 6, lane = t & 63, lr = lane & 15, lg = lane >> 4;
  const int h = wv;

  float bprr[2];
#pragma unroll
  for (int cf = 0; cf < 2; ++cf) bprr[cf] = bproj[wv * 32 + cf * 16 + lr];
  float4 blgv[4];
#pragma unroll
  for (int cf = 0; cf < 4; ++cf)
    blgv[cf] = *reinterpret_cast<const float4*>(blog + h * 64 + cf * 16 + lg * 4);

  bf16x4 oslh[2][4], osll[2][4];
#pragma unroll
  for (int cfo = 0; cfo < 2; ++cfo)
#pragma unroll
    for (int sb = 0; sb < 4; ++sb) {
      const uint4 q = *reinterpret_cast<const uint4*>(
          osltp + (size_t)(h * DH + cfo * 16 + lr) * NS + sb * 16 + lg * 4);
      union { uint u[2]; bf16x4 v; } Hc, Lc;
      Hc.u[0] = __builtin_amdgcn_perm(q.y, q.x, 0x07060302u);
      Hc.u[1] = __builtin_amdgcn_perm(q.w, q.z, 0x07060302u);
      Lc.u[0] = __builtin_amdgcn_perm(q.y, q.x, 0x05040100u);
      Lc.u[1] = __builtin_amdgcn_perm(q.w, q.z, 0x05040100u);
      oslh[cfo][sb] = Hc.v; osll[cfo][sb] = Lc.v;
    }

  for (int tile = blockIdx.x; tile < ntiles; tile += ngrid) {
    const int n0 = tile * TT;
    __syncthreads();
    {
      const int tok = t >> 3, seg = (t & 7) * 32;
      const int n = n0 + tok;
      const float* xrow = x + (size_t)n * HID + seg;
#pragma unroll
      for (int g = 0; g < 4; ++g) {
        float v[8];
        if (n < Ntok) {
          const float4* xp = (const float4*)(xrow + g * 8);
          float4 f0 = xp[0], f1 = xp[1];
          v[0]=f0.x; v[1]=f0.y; v[2]=f0.z; v[3]=f0.w;
          v[4]=f1.x; v[5]=f1.y; v[6]=f1.z; v[7]=f1.w;
        } else {
#pragma unroll
          for (int i = 0; i < 8; ++i) v[i] = 0.f;
        }
        union { ushort u[8]; bf16x8 v8; } H, L;
#pragma unroll
        for (int i = 0; i < 8; ++i) split2(v[i], H.u[i], L.u[i]);
        *reinterpret_cast<bf16x8*>(&xh[tok * 264 + seg + g * 8]) = H.v8;
        *reinterpret_cast<bf16x8*>(&xl[tok * 264 + seg + g * 8]) = L.v8;
      }
      if (t < TT) msk[t] = (n0 + t < Ntok) ? mask[n0 + t] : 0.f;
    }
    __syncthreads();

    f32x4 acc[4][4];
#pragma unroll
    for (int rf = 0; rf < 4; ++rf)
#pragma unroll
      for (int cf = 0; cf < 4; ++cf) acc[rf][cf] = zero4();
#pragma unroll
    for (int kk = 0; kk < 8; ++kk) {
      bf16x8 bx_h[4], bx_l[4];
#pragma unroll
      for (int rf = 0; rf < 4; ++rf) {
        bx_h[rf] = *reinterpret_cast<const bf16x8*>(&xh[(rf * 16 + lr) * 264 + kk * 32 + lg * 8]);
        bx_l[rf] = *reinterpret_cast<const bf16x8*>(&xl[(rf * 16 + lr) * 264 + kk * 32 + lg * 8]);
      }
#pragma unroll
      for (int cf = 0; cf < 4; ++cf) {
        const size_t bo = (size_t)(h * 64 + cf * 16 + lr) * HID + kk * 32 + lg * 8;
        bf16x8 ah = *reinterpret_cast<const bf16x8*>(wlogh + bo);
        bf16x8 al = *reinterpret_cast<const bf16x8*>(wlogl + bo);
#pragma unroll
        for (int rf = 0; rf < 4; ++rf) {
          acc[rf][cf] = MFMA(ah, bx_h[rf], acc[rf][cf]);
          acc[rf][cf] = MFMA(al, bx_h[rf], acc[rf][cf]);
          acc[rf][cf] = MFMA(ah, bx_l[rf], acc[rf][cf]);
        }
      }
    }
#pragma unroll
    for (int rf = 0; rf < 4; ++rf) {
      float mx = -1e30f;
#pragma unroll
      for (int cf = 0; cf < 4; ++cf)
#pragma unroll
        for (int r = 0; r < 4; ++r) {
          float vv = acc[rf][cf][r] + ((const float*)&blgv[cf])[r];
          acc[rf][cf][r] = vv; mx = fmaxf(mx, vv);
        }
      mx = fmaxf(mx, __shfl_xor(mx, 16)); mx = fmaxf(mx, __shfl_xor(mx, 32));
      float sm = 0.f;
#pragma unroll
      for (int cf = 0; cf < 4; ++cf)
#pragma unroll
        for (int r = 0; r < 4; ++r) { float e = __expf(acc[rf][cf][r] - mx); acc[rf][cf][r] = e; sm += e; }
      sm += __shfl_xor(sm, 16); sm += __shfl_xor(sm, 32);
      const float sc = msk[rf * 16 + lr] / sm;
#pragma unroll
      for (int cf = 0; cf < 4; ++cf)
#pragma unroll
        for (int r = 0; r < 4; ++r) acc[rf][cf][r] *= sc;
    }
    f32x4 oxacc[4][2];
#pragma unroll
    for (int rf = 0; rf < 4; ++rf) { oxacc[rf][0] = zero4(); oxacc[rf][1] = zero4(); }
#pragma unroll
    for (int rf = 0; rf < 4; ++rf) {
      uint w32[4][4];
#pragma unroll
      for (int cf = 0; cf < 4; ++cf)
#pragma unroll
        for (int r = 0; r < 4; ++r) w32[cf][r] = pack2(acc[rf][cf][r]);
#pragma unroll
      for (int sb = 0; sb < 4; ++sb) {
        union { uint u[2]; bf16x4 v; } Hc, Lc;
        Hc.u[0] = __builtin_amdgcn_perm(w32[sb][1], w32[sb][0], 0x07060302u);
        Hc.u[1] = __builtin_amdgcn_perm(w32[sb][3], w32[sb][2], 0x07060302u);
        Lc.u[0] = __builtin_amdgcn_perm(w32[sb][1], w32[sb][0], 0x05040100u);
        Lc.u[1] = __builtin_amdgcn_perm(w32[sb][3], w32[sb][2], 0x05040100u);
#pragma unroll
        for (int cfo = 0; cfo < 2; ++cfo) {
          oxacc[rf][cfo] = mfma16(Hc.v, oslh[cfo][sb], oxacc[rf][cfo]);
          oxacc[rf][cfo] = mfma16(Lc.v, oslh[cfo][sb], oxacc[rf][cfo]);
          oxacc[rf][cfo] = mfma16(Hc.v, osll[cfo][sb], oxacc[rf][cfo]);
        }
      }
    }
    __syncthreads();
#pragma unroll
    for (int rf = 0; rf < 4; ++rf)
#pragma unroll
      for (int cfo = 0; cfo < 2; ++cfo)
#pragma unroll
        for (int r = 0; r < 4; ++r) {
          const int tok = rf * 16 + lg * 4 + r;
          const int hc = h * DH + cfo * 16 + lr;
          ox32[tok * 268 + hc] = pack2(oxacc[rf][cfo][r]);
        }
    __syncthreads();
    f32x4 s2[4][2];
#pragma unroll
    for (int rf = 0; rf < 4; ++rf) { s2[rf][0] = zero4(); s2[rf][1] = zero4(); }
#pragma unroll
    for (int kk = 0; kk < 8; ++kk) {
#pragma unroll
      for (int rf = 0; rf < 4; ++rf) {
        const uint* oxp = &ox32[(rf * 16 + lr) * 268 + kk * 32 + lg * 8];
        uint4 q0 = *reinterpret_cast<const uint4*>(oxp);
        uint4 q1 = *reinterpret_cast<const uint4*>(oxp + 4);
        union { uint u[4]; bf16x8 v; } AH, AL;
        AH.u[0] = __builtin_amdgcn_perm(q0.y, q0.x, 0x07060302u);
        AH.u[1] = __builtin_amdgcn_perm(q0.w, q0.z, 0x07060302u);
        AH.u[2] = __builtin_amdgcn_perm(q1.y, q1.x, 0x07060302u);
        AH.u[3] = __builtin_amdgcn_perm(q1.w, q1.z, 0x07060302u);
        AL.u[0] = __builtin_amdgcn_perm(q0.y, q0.x, 0x05040100u);
        AL.u[1] = __builtin_amdgcn_perm(q0.w, q0.z, 0x05040100u);
        AL.u[2] = __builtin_amdgcn_perm(q1.y, q1.x, 0x05040100u);
        AL.u[3] = __builtin_amdgcn_perm(q1.w, q1.z, 0x05040100u);
#pragma unroll
        for (int cf = 0; cf < 2; ++cf) {
          const size_t bo = (size_t)(wv * 32 + cf * 16 + lr) * HID + kk * 32 + lg * 8;
          bf16x8 bh = *reinterpret_cast<const bf16x8*>(wpth + bo);
          bf16x8 bl = *reinterpret_cast<const bf16x8*>(wptl + bo);
          s2[rf][cf] = MFMA(AH.v, bh, s2[rf][cf]);
          s2[rf][cf] = MFMA(AL.v, bh, s2[rf][cf]);
          s2[rf][cf] = MFMA(AH.v, bl, s2[rf][cf]);
        }
      }
    }
    __syncthreads();
#pragma unroll
    for (int rf = 0; rf < 4; ++rf)
#pragma unroll
      for (int cf = 0; cf < 2; ++cf)
#pragma unroll
        for (int r = 0; r < 4; ++r) {
          const int tok = rf * 16 + lg * 4 + r;
          const int j = wv * 32 + cf * 16 + lr;
          const float mk = msk[tok];
          outs[tok * 268 + j] = mk * (mk * s2[rf][cf][r] + bprr[cf]);
        }
    __syncthreads();
    {
      const int tok0 = t >> 8, col = t & 255;
#pragma unroll 4
      for (int rr = 0; rr < TT / 2; ++rr) {
        const int tok = rr * 2 + tok0;
        const int n = n0 + tok;
        if (n < Ntok)
          __builtin_nontemporal_store(outs[tok * 268 + col],
                                      &out[(size_t)n * HID + col]);
      }
    }
  }
}

extern "C" void kernel_launch(void* const* d_in, const int* in_sizes, int n_in,
                              void* d_out, int out_size, void* d_ws, size_t ws_size,
                              hipStream_t stream)
{
  const float* x     = (const float*)d_in[0];
  const float* mask  = (const float*)d_in[1];
  const float* Wfx   = (const float*)d_in[2];
  const float* bfx   = (const float*)d_in[3];
  const float* Wx    = (const float*)d_in[4];
  const float* bx    = (const float*)d_in[5];
  const float* Wsl   = (const float*)d_in[6];
  const float* bsl   = (const float*)d_in[7];
  const float* Wqkv  = (const float*)d_in[8];
  const float* Wproj = (const float*)d_in[9];
  const float* bproj = (const float*)d_in[10];
  const float* temp  = (const float*)d_in[11];
  float* out = (float*)d_out;

  const int Ntok = in_sizes[0] / HID;
  const int ntiles = (Ntok + TT - 1) / TT;     // 3125 exact

  char* ws = (char*)d_ws;
  size_t off = 0;
  ushort* wlogh = (ushort*)(ws + off); off += (size_t)NQ * HID * 2;
  ushort* wlogl = (ushort*)(ws + off); off += (size_t)NQ * HID * 2;
  float*  blog  = (float*)(ws + off);  off += NQ * 4;
  ushort* wfxth = (ushort*)(ws + off); off += (size_t)HID * HID * 2;
  ushort* wpth  = (ushort*)(ws + off); off += (size_t)HID * HID * 2;
  ushort* wptl  = (ushort*)(ws + off); off += (size_t)HID * HID * 2;
  uint*   osltp = (uint*)(ws + off);   off += (size_t)NQ * DH * 4;
  float*  stb   = (float*)(ws + off);  off += (size_t)NQ * DH * 4;
  float*  normb = (float*)(ws + off);  off += NQ * 4;
  int nbp = 512;
  while (nbp > 1 && off + (size_t)nbp * PSTRIDE * 4 > ws_size) nbp >>= 1;
  float* partials = (float*)(ws + off);

  k_build_wlog<<<dim3(NQ), dim3(256), 0, stream>>>(Wx, bx, Wsl, bsl, temp, wlogh, wlogl, blog);
  k_build_wfxt<<<dim3(HID), dim3(256), 0, stream>>>(Wfx, wfxth);
  k_build_wprojt<<<dim3(HID), dim3(256), 0, stream>>>(Wproj, wpth, wptl);
  k_pass1T2<<<dim3(nbp), dim3(512), 0, stream>>>(x, mask, wlogh, blog, wfxth, bfx,
                                                 partials, Ntok, ntiles, nbp);
  k_reduce_norm<<<dim3(2), dim3(256), 0, stream>>>(partials, normb, nbp);
  k_reduce_num<<<dim3(64), dim3(256), 0, stream>>>(partials, normb, stb, nbp);
  k_sdpa<<<dim3(NH), dim3(64), 0, stream>>>(stb, Wqkv, osltp);
  k_pass3T<<<dim3(256), dim3(512), 0, stream>>>(x, mask, wlogh, wlogl, blog,
                                                osltp, wpth, wptl, bproj,
                                                out, Ntok, ntiles, 256);
}

// Round 14
// 1105.835 us; speedup vs baseline: 1.1337x; 1.0004x over previous
//
#include <hip/hip_runtime.h>

// SurfaceTransolver round 14: round-13 (best: 1106us) with ONE change:
//   pass3T launch_bounds (512,2) -> (512,1).
//   Rationale: grid 256 = 1 block/CU, so occupancy is grid-pinned; the (512,2)
//   bound was needlessly capping VGPR at 128 (counter-verified), serializing
//   the 64 weight loads per kk-loop. 256-VGPR budget lets the compiler keep
//   more weight misses in flight at zero occupancy cost.
// Everything else round-13 verbatim.

#define HID 256
#define NH  8
#define DH  32
#define NS  64
#define NQ  512
#define TT  64
#define PSTRIDE 16896

typedef short bf16x8 __attribute__((ext_vector_type(8)));
typedef short bf16x4 __attribute__((ext_vector_type(4)));
typedef float f32x4 __attribute__((ext_vector_type(4)));

#define MFMA(a,b,c) __builtin_amdgcn_mfma_f32_16x16x32_bf16((a),(b),(c),0,0,0)

__device__ __forceinline__ f32x4 mfma16(bf16x4 a, bf16x4 b, f32x4 c) {
#if __has_builtin(__builtin_amdgcn_mfma_f32_16x16x16bf16_1k)
  return __builtin_amdgcn_mfma_f32_16x16x16bf16_1k(a, b, c, 0, 0, 0);
#elif __has_builtin(__builtin_amdgcn_mfma_f32_16x16x16_bf16)
  return __builtin_amdgcn_mfma_f32_16x16x16_bf16(a, b, c, 0, 0, 0);
#else
  f32x4 d;
  asm("v_mfma_f32_16x16x16_bf16 %0, %1, %2, %3" : "=v"(d) : "v"(a), "v"(b), "v"(c));
  return d;
#endif
}

__device__ __forceinline__ f32x4 zero4() { f32x4 z; z[0]=0.f; z[1]=0.f; z[2]=0.f; z[3]=0.f; return z; }

__device__ __forceinline__ ushort bf_rne(float f) {
  unsigned u = __float_as_uint(f);
  return (ushort)((u + 0x7FFFu + ((u >> 16) & 1u)) >> 16);
}
__device__ __forceinline__ void split2(float f, ushort& h, ushort& l) {
  h = bf_rne(f);
  float fh = __uint_as_float(((unsigned)h) << 16);
  l = bf_rne(f - fh);
}
__device__ __forceinline__ uint pack2(float f) {
  ushort h, l; split2(f, h, l);
  return ((uint)h << 16) | (uint)l;
}
__device__ __forceinline__ bf16x4 pack4(float a0, float a1, float a2, float a3) {
  union { ushort u[4]; bf16x4 v; } P;
  P.u[0] = bf_rne(a0); P.u[1] = bf_rne(a1); P.u[2] = bf_rne(a2); P.u[3] = bf_rne(a3);
  return P.v;
}

// ---------------- K0a ----------------
__global__ __launch_bounds__(256) void k_build_wlog(
    const float* __restrict__ Wx, const float* __restrict__ bx,
    const float* __restrict__ Wsl, const float* __restrict__ bsl,
    const float* __restrict__ temp,
    ushort* __restrict__ wlh, ushort* __restrict__ wll, float* __restrict__ blog)
{
  const int q = blockIdx.x, k = threadIdx.x;
  const int h = q >> 6, s = q & 63;
  const float it = 1.0f / temp[h];
  float acc = 0.f;
#pragma unroll
  for (int c = 0; c < DH; ++c)
    acc = fmaf(Wx[k * HID + h * DH + c], Wsl[c * NS + s], acc);
  acc *= it;
  ushort hh, ll; split2(acc, hh, ll);
  wlh[q * HID + k] = hh; wll[q * HID + k] = ll;
  if (k == 0) {
    float b = bsl[s];
    for (int c = 0; c < DH; ++c) b = fmaf(bx[h * DH + c], Wsl[c * NS + s], b);
    blog[q] = b * it;
  }
}

// ---------------- K0b ----------------
__global__ __launch_bounds__(256) void k_build_wfxt(
    const float* __restrict__ Wfx, ushort* __restrict__ wfxth)
{
  const int c = blockIdx.x, k = threadIdx.x;
  wfxth[c * HID + k] = bf_rne(Wfx[k * HID + c]);
}

// ---------------- K0c ----------------
__global__ __launch_bounds__(256) void k_build_wprojt(
    const float* __restrict__ Wproj, ushort* __restrict__ wpth, ushort* __restrict__ wptl)
{
  const int hc = blockIdx.x, j = threadIdx.x;
  ushort hh, ll; split2(Wproj[hc * HID + j], hh, ll);
  wpth[j * HID + hc] = hh; wptl[j * HID + hc] = ll;
}

// ---------------- Pass 1T2 (round-10 verbatim, plain stores) ----------------
__global__ __launch_bounds__(512, 1) void k_pass1T2(
    const float* __restrict__ x, const float* __restrict__ mask,
    const ushort* __restrict__ wlogh, const float* __restrict__ blog,
    const ushort* __restrict__ wfxth, const float* __restrict__ bfx,
    float* __restrict__ partials, int Ntok, int ntiles, int ngrid)
{
  __shared__ ushort xh[TT * 264];
  __shared__ float msk[TT];

  const int t = threadIdx.x;
  const int wv = t >> 6, lane = t & 63, lr = lane & 15, lg = lane >> 4;
  const int h = wv;

  float blogr[4], bfxr[2];
#pragma unroll
  for (int cf = 0; cf < 4; ++cf) blogr[cf] = blog[h * 64 + cf * 16 + lr];
#pragma unroll
  for (int cf2 = 0; cf2 < 2; ++cf2) bfxr[cf2] = bfx[h * 32 + cf2 * 16 + lr];

  f32x4 pool[4][2];
#pragma unroll
  for (int cf = 0; cf < 4; ++cf) { pool[cf][0] = zero4(); pool[cf][1] = zero4(); }
  float nacc[4] = {0.f, 0.f, 0.f, 0.f};

  for (int tile = blockIdx.x; tile < ntiles; tile += ngrid) {
    const int n0 = tile * TT;
    __syncthreads();
    {
      const int tok = t >> 3, seg = (t & 7) * 32;
      const int n = n0 + tok;
      const float* xrow = x + (size_t)n * HID + seg;
#pragma unroll
      for (int g = 0; g < 4; ++g) {
        float v[8];
        if (n < Ntok) {
          const float4* xp = (const float4*)(xrow + g * 8);
          float4 f0 = xp[0], f1 = xp[1];
          v[0]=f0.x; v[1]=f0.y; v[2]=f0.z; v[3]=f0.w;
          v[4]=f1.x; v[5]=f1.y; v[6]=f1.z; v[7]=f1.w;
        } else {
#pragma unroll
          for (int i = 0; i < 8; ++i) v[i] = 0.f;
        }
        union { ushort u[8]; bf16x8 v8; } H;
#pragma unroll
        for (int i = 0; i < 8; ++i) H.u[i] = bf_rne(v[i]);
        *reinterpret_cast<bf16x8*>(&xh[tok * 264 + seg + g * 8]) = H.v8;
      }
      if (t < TT) msk[t] = (n0 + t < Ntok) ? mask[n0 + t] : 0.f;
    }
    __syncthreads();

    f32x4 acc[4][4];
#pragma unroll
    for (int rf = 0; rf < 4; ++rf)
#pragma unroll
      for (int cf = 0; cf < 4; ++cf) acc[rf][cf] = zero4();
#pragma unroll
    for (int kk = 0; kk < 8; ++kk) {
      bf16x8 a[4];
#pragma unroll
      for (int rf = 0; rf < 4; ++rf)
        a[rf] = *reinterpret_cast<const bf16x8*>(&xh[(rf * 16 + lr) * 264 + kk * 32 + lg * 8]);
#pragma unroll
      for (int cf = 0; cf < 4; ++cf) {
        bf16x8 bh = *reinterpret_cast<const bf16x8*>(wlogh + (size_t)(h * 64 + cf * 16 + lr) * HID + kk * 32 + lg * 8);
#pragma unroll
        for (int rf = 0; rf < 4; ++rf) acc[rf][cf] = MFMA(a[rf], bh, acc[rf][cf]);
      }
    }
    bf16x4 aw[4][4];
#pragma unroll
    for (int rf = 0; rf < 4; ++rf) {
#pragma unroll
      for (int r = 0; r < 4; ++r) {
        float mx = -1e30f;
#pragma unroll
        for (int cf = 0; cf < 4; ++cf) { float vv = acc[rf][cf][r] + blogr[cf]; acc[rf][cf][r] = vv; mx = fmaxf(mx, vv); }
        mx = fmaxf(mx, __shfl_xor(mx, 1)); mx = fmaxf(mx, __shfl_xor(mx, 2));
        mx = fmaxf(mx, __shfl_xor(mx, 4)); mx = fmaxf(mx, __shfl_xor(mx, 8));
        float sm = 0.f;
#pragma unroll
        for (int cf = 0; cf < 4; ++cf) { float e = __expf(acc[rf][cf][r] - mx); acc[rf][cf][r] = e; sm += e; }
        sm += __shfl_xor(sm, 1); sm += __shfl_xor(sm, 2); sm += __shfl_xor(sm, 4); sm += __shfl_xor(sm, 8);
        const float sc = msk[rf * 16 + lg * 4 + r] / sm;
#pragma unroll
        for (int cf = 0; cf < 4; ++cf) { acc[rf][cf][r] *= sc; nacc[cf] += acc[rf][cf][r]; }
      }
#pragma unroll
      for (int cf = 0; cf < 4; ++cf)
        aw[rf][cf] = pack4(acc[rf][cf][0], acc[rf][cf][1], acc[rf][cf][2], acc[rf][cf][3]);
    }
    f32x4 fa[4][2];
#pragma unroll
    for (int rf = 0; rf < 4; ++rf) { fa[rf][0] = zero4(); fa[rf][1] = zero4(); }
#pragma unroll
    for (int kk = 0; kk < 8; ++kk) {
      bf16x8 a[4];
#pragma unroll
      for (int rf = 0; rf < 4; ++rf)
        a[rf] = *reinterpret_cast<const bf16x8*>(&xh[(rf * 16 + lr) * 264 + kk * 32 + lg * 8]);
#pragma unroll
      for (int cf2 = 0; cf2 < 2; ++cf2) {
        bf16x8 bf = *reinterpret_cast<const bf16x8*>(wfxth + (size_t)(h * 32 + cf2 * 16 + lr) * HID + kk * 32 + lg * 8);
#pragma unroll
        for (int rf = 0; rf < 4; ++rf) fa[rf][cf2] = MFMA(a[rf], bf, fa[rf][cf2]);
      }
    }
#pragma unroll
    for (int rf = 0; rf < 4; ++rf) {
      bf16x4 bfrag[2];
#pragma unroll
      for (int cf2 = 0; cf2 < 2; ++cf2)
        bfrag[cf2] = pack4(fa[rf][cf2][0] + bfxr[cf2], fa[rf][cf2][1] + bfxr[cf2],
                           fa[rf][cf2][2] + bfxr[cf2], fa[rf][cf2][3] + bfxr[cf2]);
#pragma unroll
      for (int cf = 0; cf < 4; ++cf)
#pragma unroll
        for (int cf2 = 0; cf2 < 2; ++cf2)
          pool[cf][cf2] = mfma16(aw[rf][cf], bfrag[cf2], pool[cf][cf2]);
    }
  }
  float* pb = partials + (size_t)blockIdx.x * PSTRIDE;
#pragma unroll
  for (int cf = 0; cf < 4; ++cf)
#pragma unroll
    for (int cf2 = 0; cf2 < 2; ++cf2)
#pragma unroll
      for (int r = 0; r < 4; ++r) {
        const int s = cf * 16 + lg * 4 + r;
        const int hcl = cf2 * 16 + lr;
        pb[h * 2048 + s * 32 + hcl] = pool[cf][cf2][r];
      }
#pragma unroll
  for (int cf = 0; cf < 4; ++cf) {
    float v = nacc[cf];
    v += __shfl_xor(v, 16); v += __shfl_xor(v, 32);
    if (lg == 0) pb[16384 + h * 64 + cf * 16 + lr] = v;
  }
}

// ---------------- reductions ----------------
__global__ __launch_bounds__(256) void k_reduce_norm(
    const float* __restrict__ partials, float* __restrict__ normbuf, int nb)
{
  const int p = blockIdx.x * 256 + threadIdx.x;
  float s = 0.f;
  for (int b = 0; b < nb; ++b) s += partials[(size_t)b * PSTRIDE + 16384 + p];
  normbuf[p] = s;
}

__global__ __launch_bounds__(256) void k_reduce_num(
    const float* __restrict__ partials, const float* __restrict__ normbuf,
    float* __restrict__ st, int nb)
{
  const int pidx = blockIdx.x * 256 + threadIdx.x;
  float acc = 0.f;
  for (int b = 0; b < nb; ++b) acc += partials[(size_t)b * PSTRIDE + pidx];
  st[pidx] = acc / (normbuf[pidx >> 5] + 1e-5f);
}

// ---------------- SDPA ----------------
__global__ __launch_bounds__(64) void k_sdpa(
    const float* __restrict__ st, const float* __restrict__ Wqkv,
    uint* __restrict__ osltp)
{
  __shared__ float stt[NS][DH + 1];
  __shared__ float kt[NS][DH + 1];
  __shared__ float vt[NS][DH + 1];
  const int h = blockIdx.x, sr = threadIdx.x;
  for (int i = sr; i < NS * DH; i += 64) stt[i >> 5][i & 31] = st[(size_t)h * NS * DH + i];
  __syncthreads();
  float qr[DH];
#pragma unroll
  for (int c = 0; c < DH; ++c) {
    float aq = 0.f, ak = 0.f, av = 0.f;
#pragma unroll
    for (int i = 0; i < DH; ++i) {
      const float sv = stt[sr][i];
      aq = fmaf(sv, Wqkv[i * 96 + c], aq);
      ak = fmaf(sv, Wqkv[i * 96 + 32 + c], ak);
      av = fmaf(sv, Wqkv[i * 96 + 64 + c], av);
    }
    qr[c] = aq; kt[sr][c] = ak; vt[sr][c] = av;
  }
  __syncthreads();
  float sc[NS];
  float m = -1e30f;
  const float scale = 0.17677669529663687f;
#pragma unroll
  for (int tt = 0; tt < NS; ++tt) {
    float a = 0.f;
#pragma unroll
    for (int c = 0; c < DH; ++c) a = fmaf(qr[c], kt[tt][c], a);
    a *= scale; sc[tt] = a; m = fmaxf(m, a);
  }
  float sum = 0.f;
#pragma unroll
  for (int tt = 0; tt < NS; ++tt) { const float e = __expf(sc[tt] - m); sc[tt] = e; sum += e; }
  const float inv = 1.f / sum;
#pragma unroll
  for (int c = 0; c < DH; ++c) {
    float o = 0.f;
#pragma unroll
    for (int tt = 0; tt < NS; ++tt) o = fmaf(sc[tt], vt[tt][c], o);
    o *= inv;
    osltp[(h * DH + c) * NS + sr] = pack2(o);
  }
}

// ---------------- Pass 3T (r13 math; launch_bounds (512,1): VGPR unlock) ----------------
__global__ __launch_bounds__(512, 1) void k_pass3T(
    const float* __restrict__ x, const float* __restrict__ mask,
    const ushort* __restrict__ wlogh, const ushort* __restrict__ wlogl,
    const float* __restrict__ blog,
    const uint* __restrict__ osltp,
    const ushort* __restrict__ wpth, const ushort* __restrict__ wptl,
    const float* __restrict__ bproj,
    float* __restrict__ out, int Ntok, int ntiles, int ngrid)
{
  __shared__ uint smem[TT * 268];
  __shared__ float msk[TT];
  ushort* xh = (ushort*)smem;
  ushort* xl = xh + TT * 264;
  uint*   ox32 = smem;
  float*  outs = (float*)smem;

  const int t = threadIdx.x;
  const int wv = t >> 6, lane = t & 63, lr = lane & 15, lg = lane >> 4;
  const int h = wv;

  float bprr[2];
#pragma unroll
  for (int cf = 0; cf < 2; ++cf) bprr[cf] = bproj[wv * 32 + cf * 16 + lr];
  float4 blgv[4];
#pragma unroll
  for (int cf = 0; cf < 4; ++cf)
    blgv[cf] = *reinterpret_cast<const float4*>(blog + h * 64 + cf * 16 + lg * 4);

  bf16x4 oslh[2][4], osll[2][4];
#pragma unroll
  for (int cfo = 0; cfo < 2; ++cfo)
#pragma unroll
    for (int sb = 0; sb < 4; ++sb) {
      const uint4 q = *reinterpret_cast<const uint4*>(
          osltp + (size_t)(h * DH + cfo * 16 + lr) * NS + sb * 16 + lg * 4);
      union { uint u[2]; bf16x4 v; } Hc, Lc;
      Hc.u[0] = __builtin_amdgcn_perm(q.y, q.x, 0x07060302u);
      Hc.u[1] = __builtin_amdgcn_perm(q.w, q.z, 0x07060302u);
      Lc.u[0] = __builtin_amdgcn_perm(q.y, q.x, 0x05040100u);
      Lc.u[1] = __builtin_amdgcn_perm(q.w, q.z, 0x05040100u);
      oslh[cfo][sb] = Hc.v; osll[cfo][sb] = Lc.v;
    }

  for (int tile = blockIdx.x; tile < ntiles; tile += ngrid) {
    const int n0 = tile * TT;
    __syncthreads();
    {
      const int tok = t >> 3, seg = (t & 7) * 32;
      const int n = n0 + tok;
      const float* xrow = x + (size_t)n * HID + seg;
#pragma unroll
      for (int g = 0; g < 4; ++g) {
        float v[8];
        if (n < Ntok) {
          const float4* xp = (const float4*)(xrow + g * 8);
          float4 f0 = xp[0], f1 = xp[1];
          v[0]=f0.x; v[1]=f0.y; v[2]=f0.z; v[3]=f0.w;
          v[4]=f1.x; v[5]=f1.y; v[6]=f1.z; v[7]=f1.w;
        } else {
#pragma unroll
          for (int i = 0; i < 8; ++i) v[i] = 0.f;
        }
        union { ushort u[8]; bf16x8 v8; } H, L;
#pragma unroll
        for (int i = 0; i < 8; ++i) split2(v[i], H.u[i], L.u[i]);
        *reinterpret_cast<bf16x8*>(&xh[tok * 264 + seg + g * 8]) = H.v8;
        *reinterpret_cast<bf16x8*>(&xl[tok * 264 + seg + g * 8]) = L.v8;
      }
      if (t < TT) msk[t] = (n0 + t < Ntok) ? mask[n0 + t] : 0.f;
    }
    __syncthreads();

    f32x4 acc[4][4];
#pragma unroll
    for (int rf = 0; rf < 4; ++rf)
#pragma unroll
      for (int cf = 0; cf < 4; ++cf) acc[rf][cf] = zero4();
#pragma unroll
    for (int kk = 0; kk < 8; ++kk) {
      bf16x8 bx_h[4], bx_l[4];
#pragma unroll
      for (int rf = 0; rf < 4; ++rf) {
        bx_h[rf] = *reinterpret_cast<const bf16x8*>(&xh[(rf * 16 + lr) * 264 + kk * 32 + lg * 8]);
        bx_l[rf] = *reinterpret_cast<const bf16x8*>(&xl[(rf * 16 + lr) * 264 + kk * 32 + lg * 8]);
      }
#pragma unroll
      for (int cf = 0; cf < 4; ++cf) {
        const size_t bo = (size_t)(h * 64 + cf * 16 + lr) * HID + kk * 32 + lg * 8;
        bf16x8 ah = *reinterpret_cast<const bf16x8*>(wlogh + bo);
        bf16x8 al = *reinterpret_cast<const bf16x8*>(wlogl + bo);
#pragma unroll
        for (int rf = 0; rf < 4; ++rf) {
          acc[rf][cf] = MFMA(ah, bx_h[rf], acc[rf][cf]);
          acc[rf][cf] = MFMA(al, bx_h[rf], acc[rf][cf]);
          acc[rf][cf] = MFMA(ah, bx_l[rf], acc[rf][cf]);
        }
      }
    }
#pragma unroll
    for (int rf = 0; rf < 4; ++rf) {
      float mx = -1e30f;
#pragma unroll
      for (int cf = 0; cf < 4; ++cf)
#pragma unroll
        for (int r = 0; r < 4; ++r) {
          float vv = acc[rf][cf][r] + ((const float*)&blgv[cf])[r];
          acc[rf][cf][r] = vv; mx = fmaxf(mx, vv);
        }
      mx = fmaxf(mx, __shfl_xor(mx, 16)); mx = fmaxf(mx, __shfl_xor(mx, 32));
      float sm = 0.f;
#pragma unroll
      for (int cf = 0; cf < 4; ++cf)
#pragma unroll
        for (int r = 0; r < 4; ++r) { float e = __expf(acc[rf][cf][r] - mx); acc[rf][cf][r] = e; sm += e; }
      sm += __shfl_xor(sm, 16); sm += __shfl_xor(sm, 32);
      const float sc = msk[rf * 16 + lr] / sm;
#pragma unroll
      for (int cf = 0; cf < 4; ++cf)
#pragma unroll
        for (int r = 0; r < 4; ++r) acc[rf][cf][r] *= sc;
    }
    f32x4 oxacc[4][2];
#pragma unroll
    for (int rf = 0; rf < 4; ++rf) { oxacc[rf][0] = zero4(); oxacc[rf][1] = zero4(); }
#pragma unroll
    for (int rf = 0; rf < 4; ++rf) {
      uint w32[4][4];
#pragma unroll
      for (int cf = 0; cf < 4; ++cf)
#pragma unroll
        for (int r = 0; r < 4; ++r) w32[cf][r] = pack2(acc[rf][cf][r]);
#pragma unroll
      for (int sb = 0; sb < 4; ++sb) {
        union { uint u[2]; bf16x4 v; } Hc, Lc;
        Hc.u[0] = __builtin_amdgcn_perm(w32[sb][1], w32[sb][0], 0x07060302u);
        Hc.u[1] = __builtin_amdgcn_perm(w32[sb][3], w32[sb][2], 0x07060302u);
        Lc.u[0] = __builtin_amdgcn_perm(w32[sb][1], w32[sb][0], 0x05040100u);
        Lc.u[1] = __builtin_amdgcn_perm(w32[sb][3], w32[sb][2], 0x05040100u);
#pragma unroll
        for (int cfo = 0; cfo < 2; ++cfo) {
          oxacc[rf][cfo] = mfma16(Hc.v, oslh[cfo][sb], oxacc[rf][cfo]);
          oxacc[rf][cfo] = mfma16(Lc.v, oslh[cfo][sb], oxacc[rf][cfo]);
          oxacc[rf][cfo] = mfma16(Hc.v, osll[cfo][sb], oxacc[rf][cfo]);
        }
      }
    }
    __syncthreads();
#pragma unroll
    for (int rf = 0; rf < 4; ++rf)
#pragma unroll
      for (int cfo = 0; cfo < 2; ++cfo)
#pragma unroll
        for (int r = 0; r < 4; ++r) {
          const int tok = rf * 16 + lg * 4 + r;
          const int hc = h * DH + cfo * 16 + lr;
          ox32[tok * 268 + hc] = pack2(oxacc[rf][cfo][r]);
        }
    __syncthreads();
    f32x4 s2[4][2];
#pragma unroll
    for (int rf = 0; rf < 4; ++rf) { s2[rf][0] = zero4(); s2[rf][1] = zero4(); }
#pragma unroll
    for (int kk = 0; kk < 8; ++kk) {
#pragma unroll
      for (int rf = 0; rf < 4; ++rf) {
        const uint* oxp = &ox32[(rf * 16 + lr) * 268 + kk * 32 + lg * 8];
        uint4 q0 = *reinterpret_cast<const uint4*>(oxp);
        uint4 q1 = *reinterpret_cast<const uint4*>(oxp + 4);
        union { uint u[4]; bf16x8 v; } AH, AL;
        AH.u[0] = __builtin_amdgcn_perm(q0.y, q0.x, 0x07060302u);
        AH.u[1] = __builtin_amdgcn_perm(q0.w, q0.z, 0x07060302u);
        AH.u[2] = __builtin_amdgcn_perm(q1.y, q1.x, 0x07060302u);
        AH.u[3] = __builtin_amdgcn_perm(q1.w, q1.z, 0x07060302u);
        AL.u[0] = __builtin_amdgcn_perm(q0.y, q0.x, 0x05040100u);
        AL.u[1] = __builtin_amdgcn_perm(q0.w, q0.z, 0x05040100u);
        AL.u[2] = __builtin_amdgcn_perm(q1.y, q1.x, 0x05040100u);
        AL.u[3] = __builtin_amdgcn_perm(q1.w, q1.z, 0x05040100u);
#pragma unroll
        for (int cf = 0; cf < 2; ++cf) {
          const size_t bo = (size_t)(wv * 32 + cf * 16 + lr) * HID + kk * 32 + lg * 8;
          bf16x8 bh = *reinterpret_cast<const bf16x8*>(wpth + bo);
          bf16x8 bl = *reinterpret_cast<const bf16x8*>(wptl + bo);
          s2[rf][cf] = MFMA(AH.v, bh, s2[rf][cf]);
          s2[rf][cf] = MFMA(AL.v, bh, s2[rf][cf]);
          s2[rf][cf] = MFMA(AH.v, bl, s2[rf][cf]);
        }
      }
    }
    __syncthreads();
#pragma unroll
    for (int rf = 0; rf < 4; ++rf)
#pragma unroll
      for (int cf = 0; cf < 2; ++cf)
#pragma unroll
        for (int r = 0; r < 4; ++r) {
          const int tok = rf * 16 + lg * 4 + r;
          const int j = wv * 32 + cf * 16 + lr;
          const float mk = msk[tok];
          outs[tok * 268 + j] = mk * (mk * s2[rf][cf][r] + bprr[cf]);
        }
    __syncthreads();
    {
      const int tok0 = t >> 8, col = t & 255;
#pragma unroll 4
      for (int rr = 0; rr < TT / 2; ++rr) {
        const int tok = rr * 2 + tok0;
        const int n = n0 + tok;
        if (n < Ntok)
          __builtin_nontemporal_store(outs[tok * 268 + col],
                                      &out[(size_t)n * HID + col]);
      }
    }
  }
}

extern "C" void kernel_launch(void* const* d_in, const int* in_sizes, int n_in,
                              void* d_out, int out_size, void* d_ws, size_t ws_size,
                              hipStream_t stream)
{
  const float* x     = (const float*)d_in[0];
  const float* mask  = (const float*)d_in[1];
  const float* Wfx   = (const float*)d_in[2];
  const float* bfx   = (const float*)d_in[3];
  const float* Wx    = (const float*)d_in[4];
  const float* bx    = (const float*)d_in[5];
  const float* Wsl   = (const float*)d_in[6];
  const float* bsl   = (const float*)d_in[7];
  const float* Wqkv  = (const float*)d_in[8];
  const float* Wproj = (const float*)d_in[9];
  const float* bproj = (const float*)d_in[10];
  const float* temp  = (const float*)d_in[11];
  float* out = (float*)d_out;

  const int Ntok = in_sizes[0] / HID;
  const int ntiles = (Ntok + TT - 1) / TT;     // 3125 exact

  char* ws = (char*)d_ws;
  size_t off = 0;
  ushort* wlogh = (ushort*)(ws + off); off += (size_t)NQ * HID * 2;
  ushort* wlogl = (ushort*)(ws + off); off += (size_t)NQ * HID * 2;
  float*  blog  = (float*)(ws + off);  off += NQ * 4;
  ushort* wfxth = (ushort*)(ws + off); off += (size_t)HID * HID * 2;
  ushort* wpth  = (ushort*)(ws + off); off += (size_t)HID * HID * 2;
  ushort* wptl  = (ushort*)(ws + off); off += (size_t)HID * HID * 2;
  uint*   osltp = (uint*)(ws + off);   off += (size_t)NQ * DH * 4;
  float*  stb   = (float*)(ws + off);  off += (size_t)NQ * DH * 4;
  float*  normb = (float*)(ws + off);  off += NQ * 4;
  int nbp = 512;
  while (nbp > 1 && off + (size_t)nbp * PSTRIDE * 4 > ws_size) nbp >>= 1;
  float* partials = (float*)(ws + off);

  k_build_wlog<<<dim3(NQ), dim3(256), 0, stream>>>(Wx, bx, Wsl, bsl, temp, wlogh, wlogl, blog);
  k_build_wfxt<<<dim3(HID), dim3(256), 0, stream>>>(Wfx, wfxth);
  k_build_wprojt<<<dim3(HID), dim3(256), 0, stream>>>(Wproj, wpth, wptl);
  k_pass1T2<<<dim3(nbp), dim3(512), 0, stream>>>(x, mask, wlogh, blog, wfxth, bfx,
                                                 partials, Ntok, ntiles, nbp);
  k_reduce_norm<<<dim3(2), dim3(256), 0, stream>>>(partials, normb, nbp);
  k_reduce_num<<<dim3(64), dim3(256), 0, stream>>>(partials, normb, stb, nbp);
  k_sdpa<<<dim3(NH), dim3(64), 0, stream>>>(stb, Wqkv, osltp);
  k_pass3T<<<dim3(256), dim3(512), 0, stream>>>(x, mask, wlogh, wlogl, blog,
                                                osltp, wpth, wptl, bproj,
                                                out, Ntok, ntiles, 256);
}